// Round 1
// baseline (274.639 us; speedup 1.0000x reference)
//
#include <hip/hip_runtime.h>

// CosineLoss: out = mean_i( 1 - dot(a_i,b_i) / (||a_i||*||b_i||) )
// inputs: d_in[0]=cxr (N,D) f32, d_in[1]=ehr (N,D) f32; N=16384, D=2048.
//
// R4 diagnosis: L3-warm replay dispatches (FETCH=16KB) ran at the SAME
// 96 us as cold ones (FETCH=134MB) -> the old kernel was latency/issue
// bound, not BW bound. Cause: only 2 loads in flight per wave + an
// 18-op dependent shuffle chain per 2KB of data (block-wide reduce per
// row, 8 waves deep).
//
// R4 structure: ONE WAVE PER ROW. Each lane holds 32 floats of the row
// (8+8 float4, fully unrolled -> registers, no scratch), giving 16 x 1KB
// loads in flight per wave (8x MLP), and the 18-shuffle reduce runs once
// per 16KB row instead of once per 2KB (8x less DS serialization).
// VALU floor ~3.2k cyc/SIMD, DS floor ~7k cyc/CU << 102k cyc/CU memory
// floor -> genuinely BW-bound now.

#define ROWS 16384
#define COLS_V4 512                 // float4 per row (D=2048)
#define BLOCK 256                   // 4 waves per block
#define WPB (BLOCK / 64)            // 4
#define GRID 1024                   // 4096 waves total, 4 blocks/CU
#define RPW (ROWS / (GRID * WPB))   // 4 consecutive rows per wave

__global__ __launch_bounds__(BLOCK, 4) void cosine_partial_kernel(
    const float4* __restrict__ A,
    const float4* __restrict__ B,
    float* __restrict__ partial) {
    const int t    = threadIdx.x;
    const int wave = t >> 6;
    const int lane = t & 63;
    const int row0 = (blockIdx.x * WPB + wave) * RPW;   // this wave's first row

    float wloss = 0.0f;   // meaningful in lane 0 only

    for (int r = 0; r < RPW; ++r) {
        const size_t base = (size_t)(row0 + r) * COLS_V4 + lane;
        const float4* __restrict__ a = A + base;
        const float4* __restrict__ b = B + base;

        // whole row in flight: 16 independent 1KB wave-loads
        float4 va[8], vb[8];
        #pragma unroll
        for (int c = 0; c < 8; ++c) va[c] = a[(size_t)c * 64];
        #pragma unroll
        for (int c = 0; c < 8; ++c) vb[c] = b[(size_t)c * 64];

        float d = 0.0f, na = 0.0f, nb = 0.0f;
        #pragma unroll
        for (int c = 0; c < 8; ++c) {
            d  += va[c].x * vb[c].x + va[c].y * vb[c].y
                + va[c].z * vb[c].z + va[c].w * vb[c].w;
            na += va[c].x * va[c].x + va[c].y * va[c].y
                + va[c].z * va[c].z + va[c].w * va[c].w;
            nb += vb[c].x * vb[c].x + vb[c].y * vb[c].y
                + vb[c].z * vb[c].z + vb[c].w * vb[c].w;
        }

        // one wave reduce per 16KB row (was: per 2KB)
        #pragma unroll
        for (int off = 32; off > 0; off >>= 1) {
            d  += __shfl_down(d,  off, 64);
            na += __shfl_down(na, off, 64);
            nb += __shfl_down(nb, off, 64);
        }
        if (lane == 0) wloss += 1.0f - d * rsqrtf(na * nb);
    }

    __shared__ float s_loss[WPB];
    if (lane == 0) s_loss[wave] = wloss;
    __syncthreads();
    if (t == 0) {
        float s = 0.0f;
        #pragma unroll
        for (int w = 0; w < WPB; ++w) s += s_loss[w];
        partial[blockIdx.x] = s;
    }
}

__global__ __launch_bounds__(256) void cosine_reduce_kernel(
    const float* __restrict__ partial,
    float* __restrict__ out) {
    const int t = threadIdx.x;
    float s = partial[t] + partial[t + 256] + partial[t + 512] + partial[t + 768];
    #pragma unroll
    for (int off = 32; off > 0; off >>= 1) s += __shfl_down(s, off, 64);

    __shared__ float s_sum[4];
    const int wave = t >> 6;
    const int lane = t & 63;
    if (lane == 0) s_sum[wave] = s;
    __syncthreads();
    if (t == 0) {
        out[0] = (s_sum[0] + s_sum[1] + s_sum[2] + s_sum[3]) * (1.0f / (float)ROWS);
    }
}

extern "C" void kernel_launch(void* const* d_in, const int* in_sizes, int n_in,
                              void* d_out, int out_size, void* d_ws, size_t ws_size,
                              hipStream_t stream) {
    const float4* cxr = (const float4*)d_in[0];
    const float4* ehr = (const float4*)d_in[1];
    float* out     = (float*)d_out;
    float* partial = (float*)d_ws;   // GRID floats = 4 KB, fully overwritten

    cosine_partial_kernel<<<GRID, BLOCK, 0, stream>>>(cxr, ehr, partial);
    cosine_reduce_kernel<<<1, 256, 0, stream>>>(partial, out);
}